// Round 2
// baseline (7236.349 us; speedup 1.0000x reference)
//
#include <hip/hip_runtime.h>

#define N_USER     50000
#define N_TOT      150000
#define N_EDGE     2400000
#define DIM        64
#define OUT_STRIDE 256
#define SLOPE      0.2f

// Copy fp32 user/item embeddings -> contiguous ego in ws; write output cols [0,64).
// float4-vectorized: one thread = 4 floats.
__global__ void init_ego(const float* __restrict__ ue, const float* __restrict__ ie,
                         float* __restrict__ ego, float* __restrict__ out) {
    int idx = blockIdx.x * blockDim.x + threadIdx.x;          // float4 index
    if (idx >= N_TOT * DIM / 4) return;
    int n  = idx >> 4;                                        // row (16 float4s per row)
    int c4 = idx & 15;                                        // float4 col within row
    float4 v = (n < N_USER) ? ((const float4*)ue)[idx]
                            : ((const float4*)ie)[idx - N_USER * (DIM / 4)];
    ((float4*)ego)[idx] = v;
    ((float4*)out)[n * (OUT_STRIDE / 4) + c4] = v;
}

// COO SpMM scatter: side[r] += v * ego[c]. One thread = one edge x 4 dims (float4 read).
__global__ void spmm_atomic(const float* __restrict__ vals, const int* __restrict__ rows,
                            const int* __restrict__ cols, const float* __restrict__ ego,
                            float* __restrict__ side) {
    int t = blockIdx.x * blockDim.x + threadIdx.x;
    int e = t >> 4;
    if (e >= N_EDGE) return;
    int dp = (t & 15) << 2;
    int r = rows[e];
    int c = cols[e];
    float v = vals[e];
    const float4 ev = *(const float4*)(ego + c * DIM + dp);
    float* dst = side + r * DIM + dp;
    atomicAdd(dst + 0, v * ev.x);
    atomicAdd(dst + 1, v * ev.y);
    atomicAdd(dst + 2, v * ev.z);
    atomicAdd(dst + 3, v * ev.w);
}

// Per-row: new_ego = lrelu(side@Wg + bg) + lrelu((ego*side)@Wb + bb); ego <- new_ego;
// out cols [(layer+1)*64 ...) = l2norm(new_ego). One wave per row, lane = output dim.
__global__ __launch_bounds__(256) void transform(
    const float* __restrict__ Wg, const float* __restrict__ bg,
    const float* __restrict__ Wb, const float* __restrict__ bb,
    const float* __restrict__ side, float* __restrict__ ego,
    float* __restrict__ out, int layer) {
    __shared__ float sWg[DIM * DIM];
    __shared__ float sWb[DIM * DIM];
    int tid = threadIdx.x;
    for (int i = tid; i < DIM * DIM; i += 256) {
        sWg[i] = Wg[i];
        sWb[i] = Wb[i];
    }
    __syncthreads();

    int lane = tid & 63;
    int wave = tid >> 6;
    int row = blockIdx.x * 4 + wave;
    if (row >= N_TOT) return;

    float sv = side[row * DIM + lane];   // side[row][lane]
    float ev = ego[row * DIM + lane];    // ego[row][lane]
    float pv = sv * ev;                  // (ego*side)[row][lane]

    float accg = bg[lane];
    float accb = bb[lane];
    #pragma unroll
    for (int j = 0; j < DIM; ++j) {
        float sj = __shfl(sv, j, 64);    // broadcast side[row][j]
        float pj = __shfl(pv, j, 64);    // broadcast p[row][j]
        accg = fmaf(sj, sWg[j * DIM + lane], accg);
        accb = fmaf(pj, sWb[j * DIM + lane], accb);
    }
    float g = accg > 0.f ? accg : SLOPE * accg;
    float b = accb > 0.f ? accb : SLOPE * accb;
    float ne = g + b;

    ego[row * DIM + lane] = ne;          // unnormalized ego feeds next layer

    float s2 = ne * ne;
    #pragma unroll
    for (int off = 32; off > 0; off >>= 1) s2 += __shfl_xor(s2, off, 64);
    float nrm = sqrtf(s2);
    float o = ne / fmaxf(nrm, 1e-12f);
    out[row * OUT_STRIDE + (layer + 1) * DIM + lane] = o;
}

extern "C" void kernel_launch(void* const* d_in, const int* in_sizes, int n_in,
                              void* d_out, int out_size, void* d_ws, size_t ws_size,
                              hipStream_t stream) {
    const float* ue = (const float*)d_in[0];
    const float* ie = (const float*)d_in[1];
    const float* Wg[3] = {(const float*)d_in[2], (const float*)d_in[6], (const float*)d_in[10]};
    const float* bg[3] = {(const float*)d_in[3], (const float*)d_in[7], (const float*)d_in[11]};
    const float* Wb[3] = {(const float*)d_in[4], (const float*)d_in[8], (const float*)d_in[12]};
    const float* bb[3] = {(const float*)d_in[5], (const float*)d_in[9], (const float*)d_in[13]};
    const float* vals = (const float*)d_in[14];
    const int*  rows  = (const int*)d_in[15];
    const int*  cols  = (const int*)d_in[16];
    float* out = (float*)d_out;

    // Workspace layout: ego fp32 [N,64] | side fp32 [N,64]  (76.8 MB total)
    float* ego  = (float*)d_ws;
    float* side = ego + (size_t)N_TOT * DIM;

    init_ego<<<(N_TOT * DIM / 4 + 255) / 256, 256, 0, stream>>>(ue, ie, ego, out);

    for (int k = 0; k < 3; ++k) {
        hipMemsetAsync(side, 0, (size_t)N_TOT * DIM * sizeof(float), stream);
        spmm_atomic<<<(N_EDGE * 16 + 255) / 256, 256, 0, stream>>>(vals, rows, cols, ego, side);
        transform<<<(N_TOT + 3) / 4, 256, 0, stream>>>(Wg[k], bg[k], Wb[k], bb[k], side, ego, out, k);
    }
}

// Round 3
// 2883.097 us; speedup vs baseline: 2.5099x; 2.5099x over previous
//
#include <hip/hip_runtime.h>

#define N_TOT      150000
#define N_USER     50000
#define N_EDGE     2400000
#define DIM        64
#define OUT_STRIDE 256
#define SLOPE      0.2f
#define NBLK_FUSED 2048   // 8192 waves; ~18 rows/wave; W-stage traffic 2048*32KB=64MB L2

// ---- ws layout (float units) ----
// ego_a  : [0, 9.6e6)
// ego_b  : [9.6e6, 19.2e6)
// epack  : [19.2e6, 24.0e6)  (E int2 packed (col, val_bits))
// row_ptr: [24.0e6, +N+1)
// cursor : [24.35e6, +N)     (also the histogram counter array)

__global__ void init_ego(const float* __restrict__ ue, const float* __restrict__ ie,
                         float* __restrict__ ego, float* __restrict__ out) {
    int idx = blockIdx.x * blockDim.x + threadIdx.x;          // float4 index
    if (idx >= N_TOT * DIM / 4) return;
    int n  = idx >> 4;
    int c4 = idx & 15;
    float4 v = (n < N_USER) ? ((const float4*)ue)[idx]
                            : ((const float4*)ie)[idx - N_USER * (DIM / 4)];
    ((float4*)ego)[idx] = v;
    ((float4*)out)[n * (OUT_STRIDE / 4) + c4] = v;
}

__global__ void hist_rows(const int* __restrict__ rows, int* __restrict__ cnt) {
    int e = blockIdx.x * blockDim.x + threadIdx.x;
    if (e >= N_EDGE) return;
    atomicAdd(&cnt[rows[e]], 1);
}

// Single-block exclusive scan of cnt[0..N) -> row_ptr[0..N]; also resets cursor=row_ptr[i].
__global__ __launch_bounds__(1024) void scan_rows(const int* __restrict__ cnt,
                                                  int* __restrict__ row_ptr,
                                                  int* __restrict__ cursor) {
    __shared__ int ssum[1024];
    int tid = threadIdx.x;
    const int CH = (N_TOT + 1023) / 1024;                     // 147
    int beg = tid * CH;
    int end = beg + CH < N_TOT ? beg + CH : N_TOT;
    int s = 0;
    for (int i = beg; i < end; ++i) s += cnt[i];
    ssum[tid] = s;
    __syncthreads();
    for (int off = 1; off < 1024; off <<= 1) {                // Hillis-Steele inclusive
        int v = (tid >= off) ? ssum[tid - off] : 0;
        __syncthreads();
        ssum[tid] += v;
        __syncthreads();
    }
    int run = (tid == 0) ? 0 : ssum[tid - 1];
    for (int i = beg; i < end; ++i) {
        row_ptr[i] = run;
        cursor[i]  = run;
        run += cnt[i];
    }
    if (tid == 1023) row_ptr[N_TOT] = ssum[1023];
}

// Bucket edges by row: epack[pos] = (col, val_bits), pos from per-row cursor.
__global__ void scatter_edges(const int* __restrict__ rows, const int* __restrict__ cols,
                              const float* __restrict__ vals, int* __restrict__ cursor,
                              int2* __restrict__ epack) {
    int e = blockIdx.x * blockDim.x + threadIdx.x;
    if (e >= N_EDGE) return;
    int r = rows[e];
    int pos = atomicAdd(&cursor[r], 1);
    epack[pos] = make_int2(cols[e], __float_as_int(vals[e]));
}

// Fused per-layer: side = A@ego_in (CSR gather); new = lrelu(side@Wg+bg)+lrelu((ego*side)@Wb+bb);
// ego_out = new; out[:, (k+1)*64 ...] = l2norm(new). One wave per row (lane = dim), wave-stride.
__global__ __launch_bounds__(256) void fused_layer(
    const float* __restrict__ Wg, const float* __restrict__ bg,
    const float* __restrict__ Wb, const float* __restrict__ bb,
    const int* __restrict__ row_ptr, const int2* __restrict__ epack,
    const float* __restrict__ ego_in, float* __restrict__ ego_out,
    float* __restrict__ out, int layer) {
    __shared__ float sWg[DIM * DIM];
    __shared__ float sWb[DIM * DIM];
    int tid = threadIdx.x;
    for (int i = tid; i < DIM * DIM; i += 256) {
        sWg[i] = Wg[i];
        sWb[i] = Wb[i];
    }
    __syncthreads();

    int lane  = tid & 63;
    int gwave = blockIdx.x * 4 + (tid >> 6);
    const int nwaves = NBLK_FUSED * 4;
    float bgl = bg[lane];
    float bbl = bb[lane];
    float* outbase = out + (size_t)(layer + 1) * DIM;

    for (int row = gwave; row < N_TOT; row += nwaves) {
        int beg = row_ptr[row];
        int end = row_ptr[row + 1];
        float sv = 0.f;                                       // side[row][lane]
        for (int i = beg; i < end; ++i) {
            int2 ep = epack[i];                               // wave-broadcast load
            sv = fmaf(__int_as_float(ep.y), ego_in[(size_t)ep.x * DIM + lane], sv);
        }
        float ev = ego_in[(size_t)row * DIM + lane];
        float pv = sv * ev;

        float accg = bgl;
        float accb = bbl;
        #pragma unroll
        for (int j = 0; j < DIM; ++j) {
            float sj = __shfl(sv, j, 64);
            float pj = __shfl(pv, j, 64);
            accg = fmaf(sj, sWg[j * DIM + lane], accg);
            accb = fmaf(pj, sWb[j * DIM + lane], accb);
        }
        float g = accg > 0.f ? accg : SLOPE * accg;
        float b = accb > 0.f ? accb : SLOPE * accb;
        float ne = g + b;

        ego_out[(size_t)row * DIM + lane] = ne;

        float s2 = ne * ne;
        #pragma unroll
        for (int off = 32; off > 0; off >>= 1) s2 += __shfl_xor(s2, off, 64);
        float o = ne / fmaxf(sqrtf(s2), 1e-12f);
        outbase[(size_t)row * OUT_STRIDE + lane] = o;
    }
}

extern "C" void kernel_launch(void* const* d_in, const int* in_sizes, int n_in,
                              void* d_out, int out_size, void* d_ws, size_t ws_size,
                              hipStream_t stream) {
    const float* ue = (const float*)d_in[0];
    const float* ie = (const float*)d_in[1];
    const float* Wg[3] = {(const float*)d_in[2], (const float*)d_in[6], (const float*)d_in[10]};
    const float* bg[3] = {(const float*)d_in[3], (const float*)d_in[7], (const float*)d_in[11]};
    const float* Wb[3] = {(const float*)d_in[4], (const float*)d_in[8], (const float*)d_in[12]};
    const float* bb[3] = {(const float*)d_in[5], (const float*)d_in[9], (const float*)d_in[13]};
    const float* vals = (const float*)d_in[14];
    const int*  rows  = (const int*)d_in[15];
    const int*  cols  = (const int*)d_in[16];
    float* out = (float*)d_out;

    float* ego_a   = (float*)d_ws;
    float* ego_b   = ego_a + (size_t)N_TOT * DIM;             //  +9.6e6
    int2*  epack   = (int2*)(ego_b + (size_t)N_TOT * DIM);    // at 19.2e6 floats
    int*   row_ptr = (int*)(epack + N_EDGE);                  // at 24.0e6 floats
    int*   cursor  = row_ptr + (N_TOT + 64);                  // histogram counters + scatter cursors

    // ---- CSR build (once per call; adj is constant across layers) ----
    hipMemsetAsync(cursor, 0, (size_t)N_TOT * sizeof(int), stream);
    hist_rows<<<(N_EDGE + 255) / 256, 256, 0, stream>>>(rows, cursor);
    scan_rows<<<1, 1024, 0, stream>>>(cursor, row_ptr, cursor);
    scatter_edges<<<(N_EDGE + 255) / 256, 256, 0, stream>>>(rows, cols, vals, cursor, epack);

    init_ego<<<(N_TOT * DIM / 4 + 255) / 256, 256, 0, stream>>>(ue, ie, ego_a, out);

    float* ein = ego_a;
    float* eout = ego_b;
    for (int k = 0; k < 3; ++k) {
        fused_layer<<<NBLK_FUSED, 256, 0, stream>>>(Wg[k], bg[k], Wb[k], bb[k],
                                                    row_ptr, epack, ein, eout, out, k);
        float* t = ein; ein = eout; eout = t;
    }
}

// Round 4
// 1289.411 us; speedup vs baseline: 5.6121x; 2.2360x over previous
//
#include <hip/hip_runtime.h>

#define N_TOT      150000
#define N_USER     50000
#define N_EDGE     2400000
#define DIM        64
#define OUT_STRIDE 256
#define SLOPE      0.2f

// ---- ws layout ----
// ego    : [N,64] fp32 (in-place across layers)
// side   : [N,64] fp32
// epack  : [E] int2 (col, val_bits)
// row_ptr: [N+1] int
// cursor : [N] int (histogram + scatter cursors)

__global__ void init_ego(const float* __restrict__ ue, const float* __restrict__ ie,
                         float* __restrict__ ego, float* __restrict__ out) {
    int idx = blockIdx.x * blockDim.x + threadIdx.x;          // float4 index
    if (idx >= N_TOT * DIM / 4) return;
    int n  = idx >> 4;
    int c4 = idx & 15;
    float4 v = (n < N_USER) ? ((const float4*)ue)[idx]
                            : ((const float4*)ie)[idx - N_USER * (DIM / 4)];
    ((float4*)ego)[idx] = v;
    ((float4*)out)[n * (OUT_STRIDE / 4) + c4] = v;
}

__global__ void hist_rows(const int* __restrict__ rows, int* __restrict__ cnt) {
    int e = blockIdx.x * blockDim.x + threadIdx.x;
    if (e >= N_EDGE) return;
    atomicAdd(&cnt[rows[e]], 1);
}

__global__ __launch_bounds__(1024) void scan_rows(const int* __restrict__ cnt,
                                                  int* __restrict__ row_ptr,
                                                  int* __restrict__ cursor) {
    __shared__ int ssum[1024];
    int tid = threadIdx.x;
    const int CH = (N_TOT + 1023) / 1024;                     // 147
    int beg = tid * CH;
    int end = beg + CH < N_TOT ? beg + CH : N_TOT;
    int s = 0;
    for (int i = beg; i < end; ++i) s += cnt[i];
    ssum[tid] = s;
    __syncthreads();
    for (int off = 1; off < 1024; off <<= 1) {
        int v = (tid >= off) ? ssum[tid - off] : 0;
        __syncthreads();
        ssum[tid] += v;
        __syncthreads();
    }
    int run = (tid == 0) ? 0 : ssum[tid - 1];
    for (int i = beg; i < end; ++i) {
        row_ptr[i] = run;
        cursor[i]  = run;
        run += cnt[i];
    }
    if (tid == 1023) row_ptr[N_TOT] = ssum[1023];
}

__global__ void scatter_edges(const int* __restrict__ rows, const int* __restrict__ cols,
                              const float* __restrict__ vals, int* __restrict__ cursor,
                              int2* __restrict__ epack) {
    int e = blockIdx.x * blockDim.x + threadIdx.x;
    if (e >= N_EDGE) return;
    int r = rows[e];
    int pos = atomicAdd(&cursor[r], 1);
    epack[pos] = make_int2(cols[e], __float_as_int(vals[e]));
}

// side = A @ ego (CSR gather). One wave per row, lane = dim; 4-way unrolled for MLP.
__global__ __launch_bounds__(256) void spmm_gather(
    const int* __restrict__ row_ptr, const int2* __restrict__ epack,
    const float* __restrict__ ego, float* __restrict__ side) {
    int lane = threadIdx.x & 63;
    int row  = blockIdx.x * 4 + (threadIdx.x >> 6);
    if (row >= N_TOT) return;
    int beg = row_ptr[row];
    int end = row_ptr[row + 1];
    float sv = 0.f;
    int i = beg;
    for (; i + 4 <= end; i += 4) {
        int2 e0 = epack[i + 0];
        int2 e1 = epack[i + 1];
        int2 e2 = epack[i + 2];
        int2 e3 = epack[i + 3];
        float g0 = ego[(size_t)e0.x * DIM + lane];
        float g1 = ego[(size_t)e1.x * DIM + lane];
        float g2 = ego[(size_t)e2.x * DIM + lane];
        float g3 = ego[(size_t)e3.x * DIM + lane];
        sv = fmaf(__int_as_float(e0.y), g0, sv);
        sv = fmaf(__int_as_float(e1.y), g1, sv);
        sv = fmaf(__int_as_float(e2.y), g2, sv);
        sv = fmaf(__int_as_float(e3.y), g3, sv);
    }
    for (; i < end; ++i) {
        int2 e = epack[i];
        sv = fmaf(__int_as_float(e.y), ego[(size_t)e.x * DIM + lane], sv);
    }
    side[(size_t)row * DIM + lane] = sv;
}

// Dual 64x64 GEMM + LeakyReLU + add + l2norm per 64-row tile.
// p = ego*side computed during staging; ego updated IN PLACE (block owns its rows).
__global__ __launch_bounds__(256) void transform_gemm(
    const float* __restrict__ Wg, const float* __restrict__ bgv,
    const float* __restrict__ Wb, const float* __restrict__ bbv,
    const float* __restrict__ side, float* __restrict__ ego,
    float* __restrict__ out, int layer) {
    __shared__ float sST[DIM][68];     // sST[k][r] = side[R0+r][k]
    __shared__ float sPT[DIM][68];     // sPT[k][r] = (ego*side)[R0+r][k]
    __shared__ float sWg[DIM][DIM];
    __shared__ float sWb[DIM][DIM];
    int tid = threadIdx.x;
    int R0  = blockIdx.x * 64;

    #pragma unroll
    for (int it = 0; it < 4; ++it) {                          // stage W matrices
        int f = tid + it * 256;                               // float4 idx 0..1023
        float4 wg = ((const float4*)Wg)[f];
        float4 wb = ((const float4*)Wb)[f];
        int k = f >> 4, c = (f & 15) * 4;
        *(float4*)&sWg[k][c] = wg;
        *(float4*)&sWb[k][c] = wb;
    }
    #pragma unroll
    for (int it = 0; it < 4; ++it) {                          // stage side/p transposed
        int f  = tid + it * 256;
        int r  = f >> 4, k0 = (f & 15) * 4;
        int row = R0 + r;
        float4 s4 = make_float4(0.f, 0.f, 0.f, 0.f);
        float4 e4 = make_float4(0.f, 0.f, 0.f, 0.f);
        if (row < N_TOT) {
            s4 = *(const float4*)&side[(size_t)row * DIM + k0];
            e4 = *(const float4*)&ego [(size_t)row * DIM + k0];
        }
        sST[k0 + 0][r] = s4.x; sST[k0 + 1][r] = s4.y;
        sST[k0 + 2][r] = s4.z; sST[k0 + 3][r] = s4.w;
        sPT[k0 + 0][r] = s4.x * e4.x; sPT[k0 + 1][r] = s4.y * e4.y;
        sPT[k0 + 2][r] = s4.z * e4.z; sPT[k0 + 3][r] = s4.w * e4.w;
    }
    __syncthreads();

    int tx = tid & 15, ty = tid >> 4;
    int c0 = tx * 4, r0 = ty * 4;
    float ag[4][4] = {{0.f}}, ab[4][4] = {{0.f}};
    #pragma unroll 4
    for (int k = 0; k < DIM; ++k) {
        float4 s4 = *(const float4*)&sST[k][r0];
        float4 p4 = *(const float4*)&sPT[k][r0];
        float4 g4 = *(const float4*)&sWg[k][c0];
        float4 b4 = *(const float4*)&sWb[k][c0];
        float ss[4] = {s4.x, s4.y, s4.z, s4.w};
        float pp[4] = {p4.x, p4.y, p4.z, p4.w};
        float gg[4] = {g4.x, g4.y, g4.z, g4.w};
        float bw[4] = {b4.x, b4.y, b4.z, b4.w};
        #pragma unroll
        for (int i = 0; i < 4; ++i)
            #pragma unroll
            for (int j = 0; j < 4; ++j) {
                ag[i][j] = fmaf(ss[i], gg[j], ag[i][j]);
                ab[i][j] = fmaf(pp[i], bw[j], ab[i][j]);
            }
    }

    float4 bg4 = *(const float4*)&bgv[c0];
    float4 bb4 = *(const float4*)&bbv[c0];
    float bgl[4] = {bg4.x, bg4.y, bg4.z, bg4.w};
    float bbl[4] = {bb4.x, bb4.y, bb4.z, bb4.w};

    float ne[4][4];
    float ss2[4];
    #pragma unroll
    for (int i = 0; i < 4; ++i) {
        float s = 0.f;
        #pragma unroll
        for (int j = 0; j < 4; ++j) {
            float g = ag[i][j] + bgl[j];
            float b = ab[i][j] + bbl[j];
            g = g > 0.f ? g : SLOPE * g;
            b = b > 0.f ? b : SLOPE * b;
            float v = g + b;
            ne[i][j] = v;
            s = fmaf(v, v, s);
        }
        ss2[i] = s;
    }
    #pragma unroll
    for (int m = 1; m < 16; m <<= 1) {                        // reduce across tx group
        #pragma unroll
        for (int i = 0; i < 4; ++i) ss2[i] += __shfl_xor(ss2[i], m, 64);
    }

    float* outbase = out + (size_t)(layer + 1) * DIM;
    #pragma unroll
    for (int i = 0; i < 4; ++i) {
        int row = R0 + r0 + i;
        if (row >= N_TOT) break;
        float inv = 1.f / fmaxf(sqrtf(ss2[i]), 1e-12f);
        float4 e4 = make_float4(ne[i][0], ne[i][1], ne[i][2], ne[i][3]);
        float4 o4 = make_float4(ne[i][0] * inv, ne[i][1] * inv, ne[i][2] * inv, ne[i][3] * inv);
        *(float4*)&ego[(size_t)row * DIM + c0] = e4;
        *(float4*)&outbase[(size_t)row * OUT_STRIDE + c0] = o4;
    }
}

extern "C" void kernel_launch(void* const* d_in, const int* in_sizes, int n_in,
                              void* d_out, int out_size, void* d_ws, size_t ws_size,
                              hipStream_t stream) {
    const float* ue = (const float*)d_in[0];
    const float* ie = (const float*)d_in[1];
    const float* Wg[3] = {(const float*)d_in[2], (const float*)d_in[6], (const float*)d_in[10]};
    const float* bg[3] = {(const float*)d_in[3], (const float*)d_in[7], (const float*)d_in[11]};
    const float* Wb[3] = {(const float*)d_in[4], (const float*)d_in[8], (const float*)d_in[12]};
    const float* bb[3] = {(const float*)d_in[5], (const float*)d_in[9], (const float*)d_in[13]};
    const float* vals = (const float*)d_in[14];
    const int*  rows  = (const int*)d_in[15];
    const int*  cols  = (const int*)d_in[16];
    float* out = (float*)d_out;

    float* ego     = (float*)d_ws;
    float* side    = ego + (size_t)N_TOT * DIM;
    int2*  epack   = (int2*)(side + (size_t)N_TOT * DIM);
    int*   row_ptr = (int*)(epack + N_EDGE);
    int*   cursor  = row_ptr + (N_TOT + 16);

    // CSR build (adj constant across layers)
    hipMemsetAsync(cursor, 0, (size_t)N_TOT * sizeof(int), stream);
    hist_rows<<<(N_EDGE + 255) / 256, 256, 0, stream>>>(rows, cursor);
    scan_rows<<<1, 1024, 0, stream>>>(cursor, row_ptr, cursor);
    scatter_edges<<<(N_EDGE + 255) / 256, 256, 0, stream>>>(rows, cols, vals, cursor, epack);

    init_ego<<<(N_TOT * DIM / 4 + 255) / 256, 256, 0, stream>>>(ue, ie, ego, out);

    for (int k = 0; k < 3; ++k) {
        spmm_gather<<<(N_TOT + 3) / 4, 256, 0, stream>>>(row_ptr, epack, ego, side);
        transform_gemm<<<(N_TOT + 63) / 64, 256, 0, stream>>>(Wg[k], bg[k], Wb[k], bb[k],
                                                              side, ego, out, k);
    }
}

// Round 5
// 968.278 us; speedup vs baseline: 7.4734x; 1.3317x over previous
//
#include <hip/hip_runtime.h>

#define N_TOT      150000
#define N_USER     50000
#define N_EDGE     2400000
#define DIM        64
#define OUT_STRIDE 256
#define SLOPE      0.2f
#define NB_SCAN    ((N_TOT + 255) / 256)   // 587

// ---- ws layout ----
// ego    : [N,64] fp32 (in-place across layers)
// side   : [N,64] fp32
// epack  : [E] int2 (col, val_bits)
// row_ptr: [N+1] int
// cursor : [N] int (histogram counts, then scatter cursors)
// bsum   : [NB_SCAN] int

__global__ void init_ego(const float* __restrict__ ue, const float* __restrict__ ie,
                         float* __restrict__ ego, float* __restrict__ out) {
    int idx = blockIdx.x * blockDim.x + threadIdx.x;          // float4 index
    if (idx >= N_TOT * DIM / 4) return;
    int n  = idx >> 4;
    int c4 = idx & 15;
    float4 v = (n < N_USER) ? ((const float4*)ue)[idx]
                            : ((const float4*)ie)[idx - N_USER * (DIM / 4)];
    ((float4*)ego)[idx] = v;
    ((float4*)out)[n * (OUT_STRIDE / 4) + c4] = v;
}

__global__ void hist_rows(const int* __restrict__ rows, int* __restrict__ cnt) {
    int e = blockIdx.x * blockDim.x + threadIdx.x;
    if (e >= N_EDGE) return;
    atomicAdd(&cnt[rows[e]], 1);
}

// Hierarchical scan, stage 1: per-256-chunk exclusive scan + block totals.
__global__ __launch_bounds__(256) void scan_partial(const int* __restrict__ cnt,
                                                    int* __restrict__ row_ptr,
                                                    int* __restrict__ bsum) {
    __shared__ int s[256];
    int tid = threadIdx.x;
    int i = blockIdx.x * 256 + tid;
    int v = (i < N_TOT) ? cnt[i] : 0;
    s[tid] = v;
    __syncthreads();
    for (int off = 1; off < 256; off <<= 1) {                 // Hillis-Steele inclusive
        int t = (tid >= off) ? s[tid - off] : 0;
        __syncthreads();
        s[tid] += t;
        __syncthreads();
    }
    if (i < N_TOT) row_ptr[i] = s[tid] - v;                   // local exclusive
    if (tid == 255) bsum[blockIdx.x] = s[255];
}

// Stage 2: single block scans the NB_SCAN block totals (exclusive, in place).
__global__ __launch_bounds__(1024) void scan_bsums(int* __restrict__ bsum) {
    __shared__ int s[1024];
    int tid = threadIdx.x;
    int v = (tid < NB_SCAN) ? bsum[tid] : 0;
    s[tid] = v;
    __syncthreads();
    for (int off = 1; off < 1024; off <<= 1) {
        int t = (tid >= off) ? s[tid - off] : 0;
        __syncthreads();
        s[tid] += t;
        __syncthreads();
    }
    if (tid < NB_SCAN) bsum[tid] = s[tid] - v;
}

// Stage 3: add block offsets; write final row_ptr and cursor.
__global__ __launch_bounds__(256) void add_offsets(int* __restrict__ row_ptr,
                                                   const int* __restrict__ bsum,
                                                   int* __restrict__ cursor) {
    int i = blockIdx.x * 256 + threadIdx.x;
    if (i < N_TOT) {
        int v = row_ptr[i] + bsum[blockIdx.x];
        row_ptr[i] = v;
        cursor[i]  = v;
    }
    if (i == 0) row_ptr[N_TOT] = N_EDGE;
}

__global__ void scatter_edges(const int* __restrict__ rows, const int* __restrict__ cols,
                              const float* __restrict__ vals, int* __restrict__ cursor,
                              int2* __restrict__ epack) {
    int e = blockIdx.x * blockDim.x + threadIdx.x;
    if (e >= N_EDGE) return;
    int r = rows[e];
    int pos = atomicAdd(&cursor[r], 1);
    epack[pos] = make_int2(cols[e], __float_as_int(vals[e]));
}

// side = A @ ego (CSR gather). One wave per row, lane = dim; 4-way unrolled for MLP.
__global__ __launch_bounds__(256) void spmm_gather(
    const int* __restrict__ row_ptr, const int2* __restrict__ epack,
    const float* __restrict__ ego, float* __restrict__ side) {
    int lane = threadIdx.x & 63;
    int row  = blockIdx.x * 4 + (threadIdx.x >> 6);
    if (row >= N_TOT) return;
    int beg = row_ptr[row];
    int end = row_ptr[row + 1];
    float sv = 0.f;
    int i = beg;
    for (; i + 4 <= end; i += 4) {
        int2 e0 = epack[i + 0];
        int2 e1 = epack[i + 1];
        int2 e2 = epack[i + 2];
        int2 e3 = epack[i + 3];
        float g0 = ego[(size_t)e0.x * DIM + lane];
        float g1 = ego[(size_t)e1.x * DIM + lane];
        float g2 = ego[(size_t)e2.x * DIM + lane];
        float g3 = ego[(size_t)e3.x * DIM + lane];
        sv = fmaf(__int_as_float(e0.y), g0, sv);
        sv = fmaf(__int_as_float(e1.y), g1, sv);
        sv = fmaf(__int_as_float(e2.y), g2, sv);
        sv = fmaf(__int_as_float(e3.y), g3, sv);
    }
    for (; i < end; ++i) {
        int2 e = epack[i];
        sv = fmaf(__int_as_float(e.y), ego[(size_t)e.x * DIM + lane], sv);
    }
    side[(size_t)row * DIM + lane] = sv;
}

// Dual 64x64 GEMM + LeakyReLU + add + l2norm per 64-row tile.
// p = ego*side computed during staging; ego updated IN PLACE (block owns its rows).
__global__ __launch_bounds__(256) void transform_gemm(
    const float* __restrict__ Wg, const float* __restrict__ bgv,
    const float* __restrict__ Wb, const float* __restrict__ bbv,
    const float* __restrict__ side, float* __restrict__ ego,
    float* __restrict__ out, int layer) {
    __shared__ float sST[DIM][68];     // sST[k][r] = side[R0+r][k]
    __shared__ float sPT[DIM][68];     // sPT[k][r] = (ego*side)[R0+r][k]
    __shared__ float sWg[DIM][DIM];
    __shared__ float sWb[DIM][DIM];
    int tid = threadIdx.x;
    int R0  = blockIdx.x * 64;

    #pragma unroll
    for (int it = 0; it < 4; ++it) {                          // stage W matrices
        int f = tid + it * 256;                               // float4 idx 0..1023
        float4 wg = ((const float4*)Wg)[f];
        float4 wb = ((const float4*)Wb)[f];
        int k = f >> 4, c = (f & 15) * 4;
        *(float4*)&sWg[k][c] = wg;
        *(float4*)&sWb[k][c] = wb;
    }
    #pragma unroll
    for (int it = 0; it < 4; ++it) {                          // stage side/p transposed
        int f  = tid + it * 256;
        int r  = f >> 4, k0 = (f & 15) * 4;
        int row = R0 + r;
        float4 s4 = make_float4(0.f, 0.f, 0.f, 0.f);
        float4 e4 = make_float4(0.f, 0.f, 0.f, 0.f);
        if (row < N_TOT) {
            s4 = *(const float4*)&side[(size_t)row * DIM + k0];
            e4 = *(const float4*)&ego [(size_t)row * DIM + k0];
        }
        sST[k0 + 0][r] = s4.x; sST[k0 + 1][r] = s4.y;
        sST[k0 + 2][r] = s4.z; sST[k0 + 3][r] = s4.w;
        sPT[k0 + 0][r] = s4.x * e4.x; sPT[k0 + 1][r] = s4.y * e4.y;
        sPT[k0 + 2][r] = s4.z * e4.z; sPT[k0 + 3][r] = s4.w * e4.w;
    }
    __syncthreads();

    int tx = tid & 15, ty = tid >> 4;
    int c0 = tx * 4, r0 = ty * 4;
    float ag[4][4] = {{0.f}}, ab[4][4] = {{0.f}};
    #pragma unroll 4
    for (int k = 0; k < DIM; ++k) {
        float4 s4 = *(const float4*)&sST[k][r0];
        float4 p4 = *(const float4*)&sPT[k][r0];
        float4 g4 = *(const float4*)&sWg[k][c0];
        float4 b4 = *(const float4*)&sWb[k][c0];
        float ss[4] = {s4.x, s4.y, s4.z, s4.w};
        float pp[4] = {p4.x, p4.y, p4.z, p4.w};
        float gg[4] = {g4.x, g4.y, g4.z, g4.w};
        float bw[4] = {b4.x, b4.y, b4.z, b4.w};
        #pragma unroll
        for (int i = 0; i < 4; ++i)
            #pragma unroll
            for (int j = 0; j < 4; ++j) {
                ag[i][j] = fmaf(ss[i], gg[j], ag[i][j]);
                ab[i][j] = fmaf(pp[i], bw[j], ab[i][j]);
            }
    }

    float4 bg4 = *(const float4*)&bgv[c0];
    float4 bb4 = *(const float4*)&bbv[c0];
    float bgl[4] = {bg4.x, bg4.y, bg4.z, bg4.w};
    float bbl[4] = {bb4.x, bb4.y, bb4.z, bb4.w};

    float ne[4][4];
    float ss2[4];
    #pragma unroll
    for (int i = 0; i < 4; ++i) {
        float s = 0.f;
        #pragma unroll
        for (int j = 0; j < 4; ++j) {
            float g = ag[i][j] + bgl[j];
            float b = ab[i][j] + bbl[j];
            g = g > 0.f ? g : SLOPE * g;
            b = b > 0.f ? b : SLOPE * b;
            float v = g + b;
            ne[i][j] = v;
            s = fmaf(v, v, s);
        }
        ss2[i] = s;
    }
    #pragma unroll
    for (int m = 1; m < 16; m <<= 1) {                        // reduce across tx group
        #pragma unroll
        for (int i = 0; i < 4; ++i) ss2[i] += __shfl_xor(ss2[i], m, 64);
    }

    float* outbase = out + (size_t)(layer + 1) * DIM;
    #pragma unroll
    for (int i = 0; i < 4; ++i) {
        int row = R0 + r0 + i;
        if (row >= N_TOT) break;
        float inv = 1.f / fmaxf(sqrtf(ss2[i]), 1e-12f);
        float4 e4 = make_float4(ne[i][0], ne[i][1], ne[i][2], ne[i][3]);
        float4 o4 = make_float4(ne[i][0] * inv, ne[i][1] * inv, ne[i][2] * inv, ne[i][3] * inv);
        *(float4*)&ego[(size_t)row * DIM + c0] = e4;
        *(float4*)&outbase[(size_t)row * OUT_STRIDE + c0] = o4;
    }
}

extern "C" void kernel_launch(void* const* d_in, const int* in_sizes, int n_in,
                              void* d_out, int out_size, void* d_ws, size_t ws_size,
                              hipStream_t stream) {
    const float* ue = (const float*)d_in[0];
    const float* ie = (const float*)d_in[1];
    const float* Wg[3] = {(const float*)d_in[2], (const float*)d_in[6], (const float*)d_in[10]};
    const float* bg[3] = {(const float*)d_in[3], (const float*)d_in[7], (const float*)d_in[11]};
    const float* Wb[3] = {(const float*)d_in[4], (const float*)d_in[8], (const float*)d_in[12]};
    const float* bb[3] = {(const float*)d_in[5], (const float*)d_in[9], (const float*)d_in[13]};
    const float* vals = (const float*)d_in[14];
    const int*  rows  = (const int*)d_in[15];
    const int*  cols  = (const int*)d_in[16];
    float* out = (float*)d_out;

    float* ego     = (float*)d_ws;
    float* side    = ego + (size_t)N_TOT * DIM;
    int2*  epack   = (int2*)(side + (size_t)N_TOT * DIM);
    int*   row_ptr = (int*)(epack + N_EDGE);
    int*   cursor  = row_ptr + (N_TOT + 16);
    int*   bsum    = cursor + N_TOT;

    // CSR build (adj constant across layers)
    hipMemsetAsync(cursor, 0, (size_t)N_TOT * sizeof(int), stream);
    hist_rows<<<(N_EDGE + 255) / 256, 256, 0, stream>>>(rows, cursor);
    scan_partial<<<NB_SCAN, 256, 0, stream>>>(cursor, row_ptr, bsum);
    scan_bsums<<<1, 1024, 0, stream>>>(bsum);
    add_offsets<<<NB_SCAN, 256, 0, stream>>>(row_ptr, bsum, cursor);
    scatter_edges<<<(N_EDGE + 255) / 256, 256, 0, stream>>>(rows, cols, vals, cursor, epack);

    init_ego<<<(N_TOT * DIM / 4 + 255) / 256, 256, 0, stream>>>(ue, ie, ego, out);

    for (int k = 0; k < 3; ++k) {
        spmm_gather<<<(N_TOT + 3) / 4, 256, 0, stream>>>(row_ptr, epack, ego, side);
        transform_gemm<<<(N_TOT + 63) / 64, 256, 0, stream>>>(Wg[k], bg[k], Wb[k], bb[k],
                                                              side, ego, out, k);
    }
}